// Round 4
// baseline (509.916 us; speedup 1.0000x reference)
//
#include <hip/hip_runtime.h>
#include <math.h>

// LSTM fused: H=32, D=1, B=4096, T=1024.
// Lane j of a 32-lane group owns hidden unit j of one batch element (2 groups
// per wave). Recurrent weights as fp16 pairs pinned in ARCH VGPRs by issuing
// v_dot2_f32_f16 via inline asm with "v" constraints (round-3 lesson: the RA
// demotes the 64-reg weight array to AGPRs and pays v_accvgpr_read per use —
// ~100 parasitic insts/step; attributes don't reach that heuristic, operand
// class constraints do). h exchanged via wave-private LDS, no in-loop barriers
// (all sharing intra-wave, ordered by lgkmcnt).

#define HH 32
#define TT 1024
#define BPB 8
#define NTHREADS 256

typedef _Float16 half2_t __attribute__((ext_vector_type(2)));

// Force-VGPR dot2: acc += w.x*p.x + w.y*p.y  (fp32 accumulate)
__device__ __forceinline__ void dot2a(float& a, const half2_t w, const half2_t p) {
    asm("v_dot2_f32_f16 %0, %1, %2, %0" : "+v"(a) : "v"(w), "v"(p));
}

__device__ __forceinline__ float fast_sigmoid(float x) {
    float e = __builtin_amdgcn_exp2f(x * -1.4426950408889634f);
    return __builtin_amdgcn_rcpf(1.0f + e);
}

__device__ __forceinline__ float fast_tanh(float x) {
    float e = __builtin_amdgcn_exp2f(x * -2.8853900817779268f);
    return fmaf(2.0f, __builtin_amdgcn_rcpf(1.0f + e), -1.0f);
}

__global__ __attribute__((amdgpu_flat_work_group_size(NTHREADS, NTHREADS),
                          amdgpu_waves_per_eu(2, 2)))
void lstm_fused(const float* __restrict__ x,
                const float* __restrict__ W_ih,
                const float* __restrict__ W_hh,
                const float* __restrict__ b_ih,
                const float* __restrict__ b_hh,
                const float* __restrict__ fc_W,
                const float* __restrict__ fc_b,
                float* __restrict__ out)
{
    __shared__ float    xs[BPB * TT];      // 32 KB
    __shared__ _Float16 hs[BPB][HH];       // 512 B

    const int tid = threadIdx.x;
    const int bl  = tid >> 5;              // local batch index 0..7
    const int j   = tid & 31;              // hidden unit index
    const int b0  = blockIdx.x * BPB;

    // ---- stage x into LDS (coalesced float4) ----
    {
        const float4* xg  = (const float4*)(x + (size_t)b0 * TT);
        float4*       xs4 = (float4*)xs;
        #pragma unroll
        for (int it = 0; it < (BPB * TT / 4) / NTHREADS; ++it)
            xs4[it * NTHREADS + tid] = xg[it * NTHREADS + tid];
    }

    // ---- recurrent weights -> fp16 pairs: 4 gates x 16 half2 (64 regs) ----
    half2_t w2[4][HH / 2];
    #pragma unroll
    for (int g = 0; g < 4; ++g) {
        const float* wrow = W_hh + (size_t)(g * HH + j) * HH;
        #pragma unroll
        for (int k2 = 0; k2 < HH / 2; ++k2) {
            half2_t p;
            p.x = (_Float16)wrow[2 * k2 + 0];
            p.y = (_Float16)wrow[2 * k2 + 1];
            w2[g][k2] = p;
        }
    }
    float wx[4], bb[4];
    #pragma unroll
    for (int g = 0; g < 4; ++g) {
        wx[g] = W_ih[g * HH + j];                      // D == 1
        bb[g] = b_ih[g * HH + j] + b_hh[g * HH + j];
    }

    float h = 0.0f, c = 0.0f;
    __syncthreads();   // xs visible (only barrier in the kernel)

    const float*  xrow   = xs + bl * TT;
    const float4* hsrow4 = (const float4*)(&hs[bl][0]);

    #pragma unroll 4
    for (int t = 0; t < TT; ++t) {
        // Intra-wave exchange: ds_write -> ds_read ordered by lgkmcnt within
        // the wave; no __syncthreads needed.
        hs[bl][j] = (_Float16)h;

        const float xv = xrow[t];
        float a0 = fmaf(xv, wx[0], bb[0]);
        float a1 = fmaf(xv, wx[1], bb[1]);
        float a2 = fmaf(xv, wx[2], bb[2]);
        float a3 = fmaf(xv, wx[3], bb[3]);

        #pragma unroll
        for (int i = 0; i < 4; ++i) {
            const float4 q = hsrow4[i];                // broadcast ds_read_b128
            const half2_t p0 = __builtin_bit_cast(half2_t, q.x);
            const half2_t p1 = __builtin_bit_cast(half2_t, q.y);
            const half2_t p2 = __builtin_bit_cast(half2_t, q.z);
            const half2_t p3 = __builtin_bit_cast(half2_t, q.w);
            const int k2 = 4 * i;
            dot2a(a0, w2[0][k2 + 0], p0);
            dot2a(a1, w2[1][k2 + 0], p0);
            dot2a(a2, w2[2][k2 + 0], p0);
            dot2a(a3, w2[3][k2 + 0], p0);
            dot2a(a0, w2[0][k2 + 1], p1);
            dot2a(a1, w2[1][k2 + 1], p1);
            dot2a(a2, w2[2][k2 + 1], p1);
            dot2a(a3, w2[3][k2 + 1], p1);
            dot2a(a0, w2[0][k2 + 2], p2);
            dot2a(a1, w2[1][k2 + 2], p2);
            dot2a(a2, w2[2][k2 + 2], p2);
            dot2a(a3, w2[3][k2 + 2], p2);
            dot2a(a0, w2[0][k2 + 3], p3);
            dot2a(a1, w2[1][k2 + 3], p3);
            dot2a(a2, w2[2][k2 + 3], p3);
            dot2a(a3, w2[3][k2 + 3], p3);
        }

        const float gi = fast_sigmoid(a0);
        const float gf = fast_sigmoid(a1);
        const float gg = fast_tanh(a2);
        const float go = fast_sigmoid(a3);
        c = fmaf(gf, c, gi * gg);
        h = go * fast_tanh(c);
    }

    // ---- epilogue: out[b] = fc_W . h + fc_b (fp32), reduce across 32 lanes ----
    float p = h * fc_W[j];
    #pragma unroll
    for (int m = 16; m >= 1; m >>= 1)
        p += __shfl_xor(p, m, 32);
    if (j == 0)
        out[b0 + bl] = p + fc_b[0];
}

extern "C" void kernel_launch(void* const* d_in, const int* in_sizes, int n_in,
                              void* d_out, int out_size, void* d_ws, size_t ws_size,
                              hipStream_t stream) {
    const float* x    = (const float*)d_in[0];
    const float* W_ih = (const float*)d_in[1];
    const float* W_hh = (const float*)d_in[2];
    const float* b_ih = (const float*)d_in[3];
    const float* b_hh = (const float*)d_in[4];
    const float* fc_W = (const float*)d_in[5];
    const float* fc_b = (const float*)d_in[6];
    float* out = (float*)d_out;

    const int B = in_sizes[0] / TT;   // 4096 (D == 1)
    dim3 grid(B / BPB), block(NTHREADS);
    lstm_fused<<<grid, block, 0, stream>>>(x, W_ih, W_hh, b_ih, b_hh,
                                           fc_W, fc_b, out);
}

// Round 5
// 491.182 us; speedup vs baseline: 1.0381x; 1.0381x over previous
//
#include <hip/hip_runtime.h>
#include <math.h>

// LSTM fused: H=32, D=1, B=4096, T=1024.
// Round-5 structure: TWO independent batch streams per wave (lane owns unit j
// of batch bl and batch bl+8; W_hh regs shared between streams). The LSTM
// step is latency-bound (serial dot-chain -> sigmoid/tanh -> LDS round-trip
// ~500-600 cyc); with 2 phase-locked waves/SIMD those stalls were exposed
// (R1-R4 plateau ~490 us at ~40% real VALU issue). Stream B's instructions
// fill stream A's stalls via static scheduling inside one wave: ILP instead
// of TLP. Grid = 256 blocks = 1 wave/SIMD.
// x staged to LDS as fp16 (keeps LDS at 33 KB; adds ~3e-4 error, margin 3.5e-3).

#define HH 32
#define TT 1024
#define BPB 16          // batches per block (8 groups x 2 streams)
#define NTHREADS 256

typedef _Float16 half2_t __attribute__((ext_vector_type(2)));

__device__ __forceinline__ float dot2(half2_t a, half2_t b, float c) {
    return __builtin_amdgcn_fdot2(a, b, c, false);
}

__device__ __forceinline__ float fast_sigmoid(float x) {
    float e = __builtin_amdgcn_exp2f(x * -1.4426950408889634f);
    return __builtin_amdgcn_rcpf(1.0f + e);
}

__device__ __forceinline__ float fast_tanh(float x) {
    float e = __builtin_amdgcn_exp2f(x * -2.8853900817779268f);
    return fmaf(2.0f, __builtin_amdgcn_rcpf(1.0f + e), -1.0f);
}

__global__ __attribute__((amdgpu_flat_work_group_size(NTHREADS, NTHREADS),
                          amdgpu_waves_per_eu(1, 2)))
void lstm_fused(const float* __restrict__ x,
                const float* __restrict__ W_ih,
                const float* __restrict__ W_hh,
                const float* __restrict__ b_ih,
                const float* __restrict__ b_hh,
                const float* __restrict__ fc_W,
                const float* __restrict__ fc_b,
                float* __restrict__ out)
{
    __shared__ _Float16 xs[BPB * TT];      // 32 KB, x as fp16
    __shared__ _Float16 hs[BPB][HH];       // 1 KB

    const int tid = threadIdx.x;
    const int bl  = tid >> 5;              // group index 0..7 (stream A batch)
    const int j   = tid & 31;              // hidden unit index
    const int b0  = blockIdx.x * BPB;

    // ---- stage x into LDS as fp16 (coalesced float4 reads, b64 writes) ----
    {
        const float4* xg = (const float4*)(x + (size_t)b0 * TT);
        #pragma unroll
        for (int it = 0; it < (BPB * TT / 4) / NTHREADS; ++it) {
            const int q = it * NTHREADS + tid;    // quad index
            const float4 v = xg[q];
            half2_t p01, p23;
            p01.x = (_Float16)v.x;  p01.y = (_Float16)v.y;
            p23.x = (_Float16)v.z;  p23.y = (_Float16)v.w;
            half2_t* dst = (half2_t*)(xs + q * 4);
            dst[0] = p01;
            dst[1] = p23;
        }
    }

    // ---- recurrent weights -> fp16 pairs: 4 gates x 16 half2 (shared by both streams) ----
    half2_t w2[4][HH / 2];
    #pragma unroll
    for (int g = 0; g < 4; ++g) {
        const float* wrow = W_hh + (size_t)(g * HH + j) * HH;
        #pragma unroll
        for (int k2 = 0; k2 < HH / 2; ++k2) {
            half2_t p;
            p.x = (_Float16)wrow[2 * k2 + 0];
            p.y = (_Float16)wrow[2 * k2 + 1];
            w2[g][k2] = p;
        }
    }
    float wx[4], bb[4];
    #pragma unroll
    for (int g = 0; g < 4; ++g) {
        wx[g] = W_ih[g * HH + j];                      // D == 1
        bb[g] = b_ih[g * HH + j] + b_hh[g * HH + j];
    }

    float hA = 0.0f, cA = 0.0f;   // stream A: batch b0 + bl
    float hB = 0.0f, cB = 0.0f;   // stream B: batch b0 + bl + 8

    __syncthreads();   // xs visible (only barrier in the kernel)

    const _Float16* xrowA = xs + bl * TT;
    const _Float16* xrowB = xs + (bl + 8) * TT;
    const float4*   hrowA = (const float4*)(&hs[bl][0]);
    const float4*   hrowB = (const float4*)(&hs[bl + 8][0]);

    #pragma unroll 2
    for (int t = 0; t < TT; ++t) {
        // Intra-wave h exchange (ds ops ordered by lgkmcnt within the wave).
        hs[bl][j]     = (_Float16)hA;
        hs[bl + 8][j] = (_Float16)hB;

        const float xvA = (float)xrowA[t];
        const float xvB = (float)xrowB[t];

        float aA0 = fmaf(xvA, wx[0], bb[0]);
        float aA1 = fmaf(xvA, wx[1], bb[1]);
        float aA2 = fmaf(xvA, wx[2], bb[2]);
        float aA3 = fmaf(xvA, wx[3], bb[3]);
        float aB0 = fmaf(xvB, wx[0], bb[0]);
        float aB1 = fmaf(xvB, wx[1], bb[1]);
        float aB2 = fmaf(xvB, wx[2], bb[2]);
        float aB3 = fmaf(xvB, wx[3], bb[3]);

        // 8 broadcast ds_read_b128; 128 dot2 over two independent streams.
        #pragma unroll
        for (int i = 0; i < 4; ++i) {
            const float4 qA = hrowA[i];
            const float4 qB = hrowB[i];
            const half2_t pA0 = __builtin_bit_cast(half2_t, qA.x);
            const half2_t pA1 = __builtin_bit_cast(half2_t, qA.y);
            const half2_t pA2 = __builtin_bit_cast(half2_t, qA.z);
            const half2_t pA3 = __builtin_bit_cast(half2_t, qA.w);
            const half2_t pB0 = __builtin_bit_cast(half2_t, qB.x);
            const half2_t pB1 = __builtin_bit_cast(half2_t, qB.y);
            const half2_t pB2 = __builtin_bit_cast(half2_t, qB.z);
            const half2_t pB3 = __builtin_bit_cast(half2_t, qB.w);
            const int k2 = 4 * i;
            aA0 = dot2(w2[0][k2 + 0], pA0, aA0);
            aB0 = dot2(w2[0][k2 + 0], pB0, aB0);
            aA1 = dot2(w2[1][k2 + 0], pA0, aA1);
            aB1 = dot2(w2[1][k2 + 0], pB0, aB1);
            aA2 = dot2(w2[2][k2 + 0], pA0, aA2);
            aB2 = dot2(w2[2][k2 + 0], pB0, aB2);
            aA3 = dot2(w2[3][k2 + 0], pA0, aA3);
            aB3 = dot2(w2[3][k2 + 0], pB0, aB3);
            aA0 = dot2(w2[0][k2 + 1], pA1, aA0);
            aB0 = dot2(w2[0][k2 + 1], pB1, aB0);
            aA1 = dot2(w2[1][k2 + 1], pA1, aA1);
            aB1 = dot2(w2[1][k2 + 1], pB1, aB1);
            aA2 = dot2(w2[2][k2 + 1], pA1, aA2);
            aB2 = dot2(w2[2][k2 + 1], pB1, aB2);
            aA3 = dot2(w2[3][k2 + 1], pA1, aA3);
            aB3 = dot2(w2[3][k2 + 1], pB1, aB3);
            aA0 = dot2(w2[0][k2 + 2], pA2, aA0);
            aB0 = dot2(w2[0][k2 + 2], pB2, aB0);
            aA1 = dot2(w2[1][k2 + 2], pA2, aA1);
            aB1 = dot2(w2[1][k2 + 2], pB2, aB1);
            aA2 = dot2(w2[2][k2 + 2], pA2, aA2);
            aB2 = dot2(w2[2][k2 + 2], pB2, aB2);
            aA3 = dot2(w2[3][k2 + 2], pA2, aA3);
            aB3 = dot2(w2[3][k2 + 2], pB2, aB3);
            aA0 = dot2(w2[0][k2 + 3], pA3, aA0);
            aB0 = dot2(w2[0][k2 + 3], pB3, aB0);
            aA1 = dot2(w2[1][k2 + 3], pA3, aA1);
            aB1 = dot2(w2[1][k2 + 3], pB3, aB1);
            aA2 = dot2(w2[2][k2 + 3], pA3, aA2);
            aB2 = dot2(w2[2][k2 + 3], pB3, aB2);
            aA3 = dot2(w2[3][k2 + 3], pA3, aA3);
            aB3 = dot2(w2[3][k2 + 3], pB3, aB3);
        }

        // Activations + state update, two independent dependency chains.
        const float giA = fast_sigmoid(aA0);
        const float giB = fast_sigmoid(aB0);
        const float gfA = fast_sigmoid(aA1);
        const float gfB = fast_sigmoid(aB1);
        const float ggA = fast_tanh(aA2);
        const float ggB = fast_tanh(aB2);
        const float goA = fast_sigmoid(aA3);
        const float goB = fast_sigmoid(aB3);
        cA = fmaf(gfA, cA, giA * ggA);
        cB = fmaf(gfB, cB, giB * ggB);
        hA = goA * fast_tanh(cA);
        hB = goB * fast_tanh(cB);
    }

    // ---- epilogue: out[b] = fc_W . h + fc_b (fp32), reduce across 32 lanes ----
    float pA = hA * fc_W[j];
    float pB = hB * fc_W[j];
    #pragma unroll
    for (int m = 16; m >= 1; m >>= 1) {
        pA += __shfl_xor(pA, m, 32);
        pB += __shfl_xor(pB, m, 32);
    }
    if (j == 0) {
        out[b0 + bl]     = pA + fc_b[0];
        out[b0 + bl + 8] = pB + fc_b[0];
    }
}

extern "C" void kernel_launch(void* const* d_in, const int* in_sizes, int n_in,
                              void* d_out, int out_size, void* d_ws, size_t ws_size,
                              hipStream_t stream) {
    const float* x    = (const float*)d_in[0];
    const float* W_ih = (const float*)d_in[1];
    const float* W_hh = (const float*)d_in[2];
    const float* b_ih = (const float*)d_in[3];
    const float* b_hh = (const float*)d_in[4];
    const float* fc_W = (const float*)d_in[5];
    const float* fc_b = (const float*)d_in[6];
    float* out = (float*)d_out;

    const int B = in_sizes[0] / TT;   // 4096 (D == 1)
    dim3 grid(B / BPB), block(NTHREADS);
    lstm_fused<<<grid, block, 0, stream>>>(x, W_ih, W_hh, b_ih, b_hh,
                                           fc_W, fc_b, out);
}